// Round 2
// baseline (1601.197 us; speedup 1.0000x reference)
//
#include <hip/hip_runtime.h>
#include <hip/hip_bf16.h>

#define N_NODES 100000
#define N_EDGES 1600000

typedef __hip_bfloat16 bf16;

__device__ __forceinline__ float b2f(bf16 v) { return __bfloat162float(v); }

// dtype-flexible load: isf=1 -> buffer is float32, else bf16
__device__ __forceinline__ float loadf(const void* p, int i, int isf) {
    return isf ? ((const float*)p)[i] : __bfloat162float(((const bf16*)p)[i]);
}

// Detect whether float tensors are fp32 or bf16 by scanning x's raw words.
// Low 16 bits as bf16: exponent > 140 is impossible for genuine bf16 N(0,1)
// data (max exp ~129) but hits ~45% of words if the buffer is fp32 (random
// mantissa bits). flag=1 -> fp32, flag=0 -> bf16.
__global__ __launch_bounds__(256) void detect_dtype(
    const unsigned int* __restrict__ xw, int nwords, int* __restrict__ flag)
{
    __shared__ int s;
    if (threadIdx.x == 0) s = 0;
    __syncthreads();
    int c = 0;
    for (int i = threadIdx.x; i < nwords; i += 256) {
        unsigned int w = xw[i];
        unsigned int e = (w >> 7) & 0xFFu;   // exponent of low-half-as-bf16
        c += (e > 140u);
    }
    atomicAdd(&s, c);
    __syncthreads();
    if (threadIdx.x == 0) *flag = (s > 100) ? 1 : 0;
}

// One wave (64 lanes) per edge; lane = feature channel.
// feat dtype: flagp==nullptr -> bf16 fixed (h1 pass); else read *flagp.
__global__ __launch_bounds__(256) void scatter_accum(
    const void* __restrict__ feat,
    const int* __restrict__ src, const int* __restrict__ dst,
    float* __restrict__ agg, float* __restrict__ cnt,
    const int* __restrict__ flagp, int do_cnt)
{
    int isf = flagp ? *flagp : 0;
    int gid = blockIdx.x * 256 + threadIdx.x;
    int e = gid >> 6;
    int lane = gid & 63;
    if (e >= N_EDGES) return;
    int s = src[e], d = dst[e];
    float v = loadf(feat, s * 64 + lane, isf);
    atomicAdd(&agg[d * 64 + lane], v);
    if (do_cnt && lane == 0) atomicAdd(&cnt[d], 1.0f);
}

// h1[n][f] = relu(mean[n]@Wl.T + bl + x[n]@Wr.T). 4 nodes / 256-thread block.
// x,Wl,bl,Wr dtype per flag; h1 stored bf16.
__global__ __launch_bounds__(256) void node_layer1(
    const void* __restrict__ x, const float* __restrict__ agg,
    const float* __restrict__ cnt,
    const void* __restrict__ Wl, const void* __restrict__ bl,
    const void* __restrict__ Wr, bf16* __restrict__ h_out,
    const int* __restrict__ flagp)
{
    __shared__ float sWl[64][65];   // +1 pad: stride 65 -> 2-way alias (free)
    __shared__ float sWr[64][65];
    __shared__ float sm[4][64];
    __shared__ float sx[4][64];
    int isf = *flagp;
    int t = threadIdx.x;
    for (int i = t; i < 64 * 64; i += 256) {
        sWl[i >> 6][i & 63] = loadf(Wl, i, isf);
        sWr[i >> 6][i & 63] = loadf(Wr, i, isf);
    }
    int local = t >> 6;
    int f = t & 63;
    int node = blockIdx.x * 4 + local;   // N_NODES % 4 == 0
    float c = cnt[node];
    float inv = 1.0f / fmaxf(c, 1.0f);
    sm[local][f] = agg[node * 64 + f] * inv;
    sx[local][f] = loadf(x, node * 64 + f, isf);
    __syncthreads();
    float acc = loadf(bl, f, isf);
#pragma unroll
    for (int k = 0; k < 64; k++)
        acc += sm[local][k] * sWl[f][k] + sx[local][k] * sWr[f][k];
    h_out[node * 64 + f] = __float2bfloat16(fmaxf(acc, 0.0f));
}

// Layer 2 fused with edge-scorer projection: h2 never materialized.
// s_src[n] = h2[n].Wlin[0:64], s_dst[n] = h2[n].Wlin[64:128]
__global__ __launch_bounds__(256) void node_layer2(
    const bf16* __restrict__ h1, const float* __restrict__ agg,
    const float* __restrict__ cnt,
    const void* __restrict__ Wl, const void* __restrict__ bl,
    const void* __restrict__ Wr, const void* __restrict__ Wlin,
    float* __restrict__ s_src, float* __restrict__ s_dst,
    const int* __restrict__ flagp)
{
    __shared__ float sWl[64][65];
    __shared__ float sWr[64][65];
    __shared__ float sm[4][64];
    __shared__ float sx[4][64];
    int isf = *flagp;
    int t = threadIdx.x;
    for (int i = t; i < 64 * 64; i += 256) {
        sWl[i >> 6][i & 63] = loadf(Wl, i, isf);
        sWr[i >> 6][i & 63] = loadf(Wr, i, isf);
    }
    int local = t >> 6;
    int f = t & 63;
    int node = blockIdx.x * 4 + local;
    float c = cnt[node];
    float inv = 1.0f / fmaxf(c, 1.0f);
    sm[local][f] = agg[node * 64 + f] * inv;
    sx[local][f] = b2f(h1[node * 64 + f]);
    __syncthreads();
    float acc = loadf(bl, f, isf);
#pragma unroll
    for (int k = 0; k < 64; k++)
        acc += sm[local][k] * sWl[f][k] + sx[local][k] * sWr[f][k];
    float h = fmaxf(acc, 0.0f);
    float a = h * loadf(Wlin, f, isf);
    float b = h * loadf(Wlin, 64 + f, isf);
    for (int off = 32; off; off >>= 1) {   // wave(64) reduction
        a += __shfl_down(a, off);
        b += __shfl_down(b, off);
    }
    if (f == 0) { s_src[node] = a; s_dst[node] = b; }
}

__global__ __launch_bounds__(256) void edge_out_kernel(
    const int* __restrict__ src, const int* __restrict__ dst,
    const float* __restrict__ s_src, const float* __restrict__ s_dst,
    const void* __restrict__ blin, void* __restrict__ out,
    const int* __restrict__ flagp)
{
    int isf = *flagp;
    int e = blockIdx.x * 256 + threadIdx.x;
    if (e >= N_EDGES) return;
    float v = s_src[src[e]] + s_dst[dst[e]] + loadf(blin, 0, isf);
    if (isf) ((float*)out)[e] = v;
    else     ((bf16*)out)[e] = __float2bfloat16(v);
}

extern "C" void kernel_launch(void* const* d_in, const int* in_sizes, int n_in,
                              void* d_out, int out_size, void* d_ws, size_t ws_size,
                              hipStream_t stream) {
    const void* x    = d_in[0];
    const int*  ei   = (const int*)d_in[1];
    const void* W1l  = d_in[2];
    const void* b1l  = d_in[3];
    const void* W1r  = d_in[4];
    const void* W2l  = d_in[5];
    const void* b2l  = d_in[6];
    const void* W2r  = d_in[7];
    const void* Wlin = d_in[8];
    const void* blin = d_in[9];

    const int* src = ei;
    const int* dst = ei + N_EDGES;

    float* agg  = (float*)d_ws;                        // N*64 fp32  (25.6 MB)
    float* cnt  = agg  + (size_t)N_NODES * 64;         // N    fp32  (0.4 MB)
    bf16*  h1   = (bf16*)(cnt + N_NODES);              // N*64 bf16  (12.8 MB)
    float* ssrc = (float*)(h1 + (size_t)N_NODES * 64); // N    fp32
    float* sdst = ssrc + N_NODES;                      // N    fp32
    int*   flag = (int*)(sdst + N_NODES);              // 1 int
    // total ~39.6 MB

    const int scatter_blocks = (N_EDGES * 64) / 256;   // 400000, exact
    const int node_blocks = N_NODES / 4;               // 25000, exact
    const int edge_blocks = N_EDGES / 256;             // 6250, exact

    detect_dtype<<<1, 256, 0, stream>>>((const unsigned int*)x, 65536, flag);

    // Layer 1
    hipMemsetAsync(agg, 0, ((size_t)N_NODES * 64 + N_NODES) * sizeof(float), stream);
    scatter_accum<<<scatter_blocks, 256, 0, stream>>>(x, src, dst, agg, cnt, flag, 1);
    node_layer1<<<node_blocks, 256, 0, stream>>>(x, agg, cnt, W1l, b1l, W1r, h1, flag);

    // Layer 2 (reuse agg; cnt identical — same edge list)
    hipMemsetAsync(agg, 0, (size_t)N_NODES * 64 * sizeof(float), stream);
    scatter_accum<<<scatter_blocks, 256, 0, stream>>>(h1, src, dst, agg, nullptr, nullptr, 0);
    node_layer2<<<node_blocks, 256, 0, stream>>>(h1, agg, cnt, W2l, b2l, W2r, Wlin, ssrc, sdst, flag);

    // Edge scores
    edge_out_kernel<<<edge_blocks, 256, 0, stream>>>(src, dst, ssrc, sdst, blin, d_out, flag);
}

// Round 6
// 946.771 us; speedup vs baseline: 1.6912x; 1.6912x over previous
//
#include <hip/hip_runtime.h>
#include <hip/hip_bf16.h>

#define N_NODES 100000
#define N_EDGES 1600000

// All float tensors are genuine fp32 (confirmed R3-vs-R5: bf16 misread -> NaN).
// Internal MFMA compute converts to bf16 in registers; output written fp32.

typedef __hip_bfloat16 bf16;
typedef short short8 __attribute__((ext_vector_type(8)));
typedef float f32x4 __attribute__((ext_vector_type(4)));

__device__ __forceinline__ short f2bs(float f) {
    bf16 h = __float2bfloat16(f);
    short s; __builtin_memcpy(&s, &h, 2); return s;
}

// 8 consecutive fp32 -> bf16 bits (two float4 loads)
__device__ __forceinline__ short8 cvt8(const float* __restrict__ p) {
    float4 v0 = *(const float4*)p;
    float4 v1 = *(const float4*)(p + 4);
    short8 t;
    t[0] = f2bs(v0.x); t[1] = f2bs(v0.y); t[2] = f2bs(v0.z); t[3] = f2bs(v0.w);
    t[4] = f2bs(v1.x); t[5] = f2bs(v1.y); t[6] = f2bs(v1.z); t[7] = f2bs(v1.w);
    return t;
}

// 8 consecutive fp32 scaled -> bf16 bits
__device__ __forceinline__ short8 cvt8s(const float* __restrict__ p, float s) {
    float4 v0 = *(const float4*)p;
    float4 v1 = *(const float4*)(p + 4);
    short8 t;
    t[0] = f2bs(v0.x * s); t[1] = f2bs(v0.y * s); t[2] = f2bs(v0.z * s); t[3] = f2bs(v0.w * s);
    t[4] = f2bs(v1.x * s); t[5] = f2bs(v1.y * s); t[6] = f2bs(v1.z * s); t[7] = f2bs(v1.w * s);
    return t;
}

// 8 consecutive bf16 (16B vector load)
__device__ __forceinline__ short8 load8bf(const bf16* __restrict__ p, long idx) {
    return *(const short8*)((const short*)p + idx);
}

// One wave (64 lanes) per edge; lane = feature channel. fp32 feat.
__global__ __launch_bounds__(256) void scatter_accum_f32(
    const float* __restrict__ feat,
    const int* __restrict__ src, const int* __restrict__ dst,
    float* __restrict__ agg, float* __restrict__ cnt, int do_cnt)
{
    int gid = blockIdx.x * 256 + threadIdx.x;
    int e = gid >> 6;
    int lane = gid & 63;
    if (e >= N_EDGES) return;
    int s = src[e], d = dst[e];
    float v = feat[(long)s * 64 + lane];
    atomicAdd(&agg[(long)d * 64 + lane], v);
    if (do_cnt && lane == 0) atomicAdd(&cnt[d], 1.0f);
}

// bf16 feat variant (h1 lives in ws as bf16)
__global__ __launch_bounds__(256) void scatter_accum_bf16(
    const bf16* __restrict__ feat,
    const int* __restrict__ src, const int* __restrict__ dst,
    float* __restrict__ agg)
{
    int gid = blockIdx.x * 256 + threadIdx.x;
    int e = gid >> 6;
    int lane = gid & 63;
    if (e >= N_EDGES) return;
    int s = src[e], d = dst[e];
    float v = __bfloat162float(feat[(long)s * 64 + lane]);
    atomicAdd(&agg[(long)d * 64 + lane], v);
}

// ---- MFMA node layers -------------------------------------------------
// C[node][f] = relu( mean[node]·Wl[f] + self[node]·Wr[f] + bias[f] )
// as a K=128 GEMM: A = [mean || self], B = [Wl ; Wr].
// mfma_f32_16x16x32_bf16 layouts (measured, m89):
//   A: m=lane&15, k = quad*8+j   B: n=lane&15, k = quad*8+j
//   C/D: col=lane&15 (=f), row=quad*4+reg (=node)
// Per wave: 16 nodes, 4 f-tiles x 4 k-chunks = 16 MFMA. No LDS.

// SELF_BF16=true -> self buffer is bf16 (h1); else fp32 (x)
template <bool SELF_BF16>
__device__ __forceinline__ void load_afrags(
    short8* a, const float* __restrict__ agg, const float* __restrict__ cnt,
    const void* __restrict__ self, int na, int quad)
{
    float inv = 1.0f / fmaxf(cnt[na], 1.0f);
    const float* ar = agg + (long)na * 64;
#pragma unroll
    for (int c = 0; c < 2; c++)             // mean part, k = 0..63
        a[c] = cvt8s(ar + c * 32 + quad * 8, inv);
#pragma unroll
    for (int c = 0; c < 2; c++) {           // self part, k = 64..127
        long idx = (long)na * 64 + c * 32 + quad * 8;
        if (SELF_BF16) a[2 + c] = load8bf((const bf16*)self, idx);
        else           a[2 + c] = cvt8((const float*)self + idx);
    }
}

__device__ __forceinline__ short8 load_bfrag(
    const float* __restrict__ Wl, const float* __restrict__ Wr,
    int f, int c, int quad)
{
    if (c < 2) return cvt8(Wl + (long)f * 64 + c * 32 + quad * 8);
    return cvt8(Wr + (long)f * 64 + (c - 2) * 32 + quad * 8);
}

// Layer 1: writes h1 (bf16)
__global__ __launch_bounds__(256) void node_layer1_mfma(
    const float* __restrict__ x, const float* __restrict__ agg,
    const float* __restrict__ cnt,
    const float* __restrict__ Wl, const float* __restrict__ bl,
    const float* __restrict__ Wr, bf16* __restrict__ h_out)
{
    int tid = threadIdx.x;
    int wave = tid >> 6, lane = tid & 63;
    int quad = lane >> 4, n16 = lane & 15;
    int nb = (blockIdx.x * 4 + wave) * 16;          // first node of this wave

    int node_a = nb + n16;
    int na = node_a < N_NODES ? node_a : N_NODES - 1;
    short8 a[4];
    load_afrags<false>(a, agg, cnt, x, na, quad);

#pragma unroll
    for (int t = 0; t < 4; t++) {                   // f-tile
        int f = 16 * t + n16;
        f32x4 acc = {0.f, 0.f, 0.f, 0.f};
#pragma unroll
        for (int c = 0; c < 4; c++) {
            short8 b = load_bfrag(Wl, Wr, f, c, quad);
            acc = __builtin_amdgcn_mfma_f32_16x16x32_bf16(a[c], b, acc, 0, 0, 0);
        }
        float bias = bl[f];
#pragma unroll
        for (int r = 0; r < 4; r++) {
            int node = nb + quad * 4 + r;
            if (node < N_NODES)
                h_out[(long)node * 64 + f] = __float2bfloat16(fmaxf(acc[r] + bias, 0.0f));
        }
    }
}

// Layer 2 fused with edge-scorer projection; h2 never materialized.
// s_src[n] = h2[n].Wlin[0:64], s_dst[n] = h2[n].Wlin[64:128]
__global__ __launch_bounds__(256) void node_layer2_mfma(
    const bf16* __restrict__ h1, const float* __restrict__ agg,
    const float* __restrict__ cnt,
    const float* __restrict__ Wl, const float* __restrict__ bl,
    const float* __restrict__ Wr, const float* __restrict__ Wlin,
    float* __restrict__ s_src, float* __restrict__ s_dst)
{
    int tid = threadIdx.x;
    int wave = tid >> 6, lane = tid & 63;
    int quad = lane >> 4, n16 = lane & 15;
    int nb = (blockIdx.x * 4 + wave) * 16;

    int node_a = nb + n16;
    int na = node_a < N_NODES ? node_a : N_NODES - 1;
    short8 a[4];
    load_afrags<true>(a, agg, cnt, h1, na, quad);

    float sa[4] = {0.f, 0.f, 0.f, 0.f};
    float sb[4] = {0.f, 0.f, 0.f, 0.f};
#pragma unroll
    for (int t = 0; t < 4; t++) {
        int f = 16 * t + n16;
        f32x4 acc = {0.f, 0.f, 0.f, 0.f};
#pragma unroll
        for (int c = 0; c < 4; c++) {
            short8 b = load_bfrag(Wl, Wr, f, c, quad);
            acc = __builtin_amdgcn_mfma_f32_16x16x32_bf16(a[c], b, acc, 0, 0, 0);
        }
        float bias = bl[f];
        float wa = Wlin[f];
        float wb = Wlin[64 + f];
#pragma unroll
        for (int r = 0; r < 4; r++) {
            float h = fmaxf(acc[r] + bias, 0.0f);
            sa[r] += h * wa;
            sb[r] += h * wb;
        }
    }
    // reduce over the 16 lanes (n16) sharing a quad
#pragma unroll
    for (int m = 1; m < 16; m <<= 1) {
#pragma unroll
        for (int r = 0; r < 4; r++) {
            sa[r] += __shfl_xor(sa[r], m);
            sb[r] += __shfl_xor(sb[r], m);
        }
    }
    if (n16 == 0) {
#pragma unroll
        for (int r = 0; r < 4; r++) {
            int node = nb + quad * 4 + r;
            if (node < N_NODES) { s_src[node] = sa[r]; s_dst[node] = sb[r]; }
        }
    }
}

__global__ __launch_bounds__(256) void edge_out_kernel(
    const int* __restrict__ src, const int* __restrict__ dst,
    const float* __restrict__ s_src, const float* __restrict__ s_dst,
    const float* __restrict__ blin, float* __restrict__ out)
{
    int e = blockIdx.x * 256 + threadIdx.x;
    if (e >= N_EDGES) return;
    out[e] = s_src[src[e]] + s_dst[dst[e]] + blin[0];
}

extern "C" void kernel_launch(void* const* d_in, const int* in_sizes, int n_in,
                              void* d_out, int out_size, void* d_ws, size_t ws_size,
                              hipStream_t stream) {
    const float* x    = (const float*)d_in[0];
    const int*   ei   = (const int*)d_in[1];
    const float* W1l  = (const float*)d_in[2];
    const float* b1l  = (const float*)d_in[3];
    const float* W1r  = (const float*)d_in[4];
    const float* W2l  = (const float*)d_in[5];
    const float* b2l  = (const float*)d_in[6];
    const float* W2r  = (const float*)d_in[7];
    const float* Wlin = (const float*)d_in[8];
    const float* blin = (const float*)d_in[9];
    float* out = (float*)d_out;

    const int* src = ei;
    const int* dst = ei + N_EDGES;

    // Workspace layout (39.6 MB total — same extent R2 proved safe)
    float* agg  = (float*)d_ws;                        // N*64 fp32 (25.6 MB)
    float* cnt  = agg  + (size_t)N_NODES * 64;         // N    fp32 ( 0.4 MB)
    bf16*  h1   = (bf16*)(cnt + N_NODES);              // N*64 bf16 (12.8 MB)
    float* ssrc = (float*)(h1 + (size_t)N_NODES * 64); // N    fp32
    float* sdst = ssrc + N_NODES;                      // N    fp32

    const int scatter_blocks = (N_EDGES * 64) / 256;   // 400000, exact
    const int node_blocks = (N_NODES + 63) / 64;       // 1563 (64 nodes/block)
    const int edge_blocks = N_EDGES / 256;             // 6250, exact

    // Layer 1
    (void)hipMemsetAsync(agg, 0, ((size_t)N_NODES * 64 + N_NODES) * sizeof(float), stream);
    scatter_accum_f32<<<scatter_blocks, 256, 0, stream>>>(x, src, dst, agg, cnt, 1);
    node_layer1_mfma<<<node_blocks, 256, 0, stream>>>(x, agg, cnt, W1l, b1l, W1r, h1);

    // Layer 2 (re-zero agg; cnt identical — same edge list)
    (void)hipMemsetAsync(agg, 0, (size_t)N_NODES * 64 * sizeof(float), stream);
    scatter_accum_bf16<<<scatter_blocks, 256, 0, stream>>>(h1, src, dst, agg);
    node_layer2_mfma<<<node_blocks, 256, 0, stream>>>(h1, agg, cnt, W2l, b2l, W2r, Wlin, ssrc, sdst);

    // Edge scores
    edge_out_kernel<<<edge_blocks, 256, 0, stream>>>(src, dst, ssrc, sdst, blin, out);
}

// Round 7
// 482.377 us; speedup vs baseline: 3.3194x; 1.9627x over previous
//
#include <hip/hip_runtime.h>
#include <hip/hip_bf16.h>

#define N_NODES 100000
#define N_EDGES 1600000
#define SCAN_BLOCKS 391          // ceil(100000/256)

// Float tensors are genuine fp32 (confirmed R3-vs-R5). Internal MFMA compute
// in bf16; output fp32.

typedef __hip_bfloat16 bf16;
typedef short short8 __attribute__((ext_vector_type(8)));
typedef float f32x4 __attribute__((ext_vector_type(4)));

__device__ __forceinline__ short f2bs(float f) {
    bf16 h = __float2bfloat16(f);
    short s; __builtin_memcpy(&s, &h, 2); return s;
}

// 8 consecutive fp32 -> bf16 bits (two float4 loads)
__device__ __forceinline__ short8 cvt8(const float* __restrict__ p) {
    float4 v0 = *(const float4*)p;
    float4 v1 = *(const float4*)(p + 4);
    short8 t;
    t[0] = f2bs(v0.x); t[1] = f2bs(v0.y); t[2] = f2bs(v0.z); t[3] = f2bs(v0.w);
    t[4] = f2bs(v1.x); t[5] = f2bs(v1.y); t[6] = f2bs(v1.z); t[7] = f2bs(v1.w);
    return t;
}

// 8 consecutive bf16 (16B vector load)
__device__ __forceinline__ short8 load8bf(const bf16* __restrict__ p, long idx) {
    return *(const short8*)((const short*)p + idx);
}

__device__ __forceinline__ float ldf(const float* __restrict__ p, long i) { return p[i]; }
__device__ __forceinline__ float ldf(const bf16*  __restrict__ p, long i) { return __bfloat162float(p[i]); }

// ---- CSR build --------------------------------------------------------

__global__ __launch_bounds__(256) void hist_kernel(
    const int* __restrict__ dst, int* __restrict__ deg)
{
    int e = blockIdx.x * 256 + threadIdx.x;
    if (e < N_EDGES) atomicAdd(&deg[dst[e]], 1);
}

// Per-256-block exclusive scan; writes excl results into offs, block sums to bsum.
__global__ __launch_bounds__(256) void scan1_kernel(
    const int* __restrict__ deg, int* __restrict__ offs, int* __restrict__ bsum)
{
    __shared__ int tmp[256];
    int t = threadIdx.x;
    int i = blockIdx.x * 256 + t;
    int v = (i < N_NODES) ? deg[i] : 0;
    tmp[t] = v;
    __syncthreads();
#pragma unroll
    for (int off = 1; off < 256; off <<= 1) {
        int add = (t >= off) ? tmp[t - off] : 0;
        __syncthreads();
        tmp[t] += add;
        __syncthreads();
    }
    if (i < N_NODES) offs[i] = tmp[t] - v;          // exclusive
    if (t == 255) bsum[blockIdx.x] = tmp[255];
}

// Single block scans the SCAN_BLOCKS block sums (exclusive, in place).
__global__ __launch_bounds__(512) void scan2_kernel(int* __restrict__ bsum)
{
    __shared__ int tmp[512];
    int t = threadIdx.x;
    int v = (t < SCAN_BLOCKS) ? bsum[t] : 0;
    tmp[t] = v;
    __syncthreads();
#pragma unroll
    for (int off = 1; off < 512; off <<= 1) {
        int add = (t >= off) ? tmp[t - off] : 0;
        __syncthreads();
        tmp[t] += add;
        __syncthreads();
    }
    if (t < SCAN_BLOCKS) bsum[t] = tmp[t] - v;      // exclusive
}

// Add block offsets; mirror into woff (fill cursors); set offs[N] = E.
__global__ __launch_bounds__(256) void scan3_kernel(
    int* __restrict__ offs, int* __restrict__ woff, const int* __restrict__ bsum)
{
    int i = blockIdx.x * 256 + threadIdx.x;
    if (i < N_NODES) {
        int v = offs[i] + bsum[blockIdx.x];
        offs[i] = v;
        woff[i] = v;
    }
    if (i == 0) offs[N_NODES] = N_EDGES;
}

__global__ __launch_bounds__(256) void fill_kernel(
    const int* __restrict__ src, const int* __restrict__ dst,
    int* __restrict__ woff, int* __restrict__ csr)
{
    int e = blockIdx.x * 256 + threadIdx.x;
    if (e >= N_EDGES) return;
    int pos = atomicAdd(&woff[dst[e]], 1);
    csr[pos] = src[e];
}

// ---- Mean aggregation (gather, no atomics) ----------------------------
// One wave per node, lane = feature channel. Writes mean as bf16.
template <typename T>
__global__ __launch_bounds__(256) void aggregate_mean(
    const T* __restrict__ feat, const int* __restrict__ offs,
    const int* __restrict__ csr, bf16* __restrict__ mean)
{
    int wave = threadIdx.x >> 6, lane = threadIdx.x & 63;
    int n = blockIdx.x * 4 + wave;
    if (n >= N_NODES) return;
    int beg = offs[n], end = offs[n + 1];
    float acc = 0.0f;
    int i = beg;
    for (; i + 4 <= end; i += 4) {      // 4 independent row-gathers in flight
        int s0 = csr[i], s1 = csr[i + 1], s2 = csr[i + 2], s3 = csr[i + 3];
        acc += ldf(feat, (long)s0 * 64 + lane) + ldf(feat, (long)s1 * 64 + lane)
             + ldf(feat, (long)s2 * 64 + lane) + ldf(feat, (long)s3 * 64 + lane);
    }
    for (; i < end; i++) acc += ldf(feat, (long)csr[i] * 64 + lane);
    int d = end - beg;
    float inv = d > 0 ? 1.0f / (float)d : 0.0f;
    mean[(long)n * 64 + lane] = __float2bfloat16(acc * inv);
}

// ---- MFMA node layers -------------------------------------------------
// C[node][f] = relu( mean[node]·Wl[f] + self[node]·Wr[f] + bias[f] )
// as a K=128 GEMM: A = [mean || self], B = [Wl ; Wr].
// mfma_f32_16x16x32_bf16: A: m=lane&15, k(chunk c) = c*32 + quad*8 + j
// C/D: col=lane&15 (=f), row=quad*4+reg (=node). 16 nodes/wave, 16 MFMA. No LDS.

template <bool SELF_BF16>
__device__ __forceinline__ void load_afrags(
    short8* a, const bf16* __restrict__ mean,
    const void* __restrict__ self, int na, int quad)
{
#pragma unroll
    for (int c = 0; c < 2; c++)             // mean part, k = 0..63
        a[c] = load8bf(mean, (long)na * 64 + c * 32 + quad * 8);
#pragma unroll
    for (int c = 0; c < 2; c++) {           // self part, k = 64..127
        long idx = (long)na * 64 + c * 32 + quad * 8;
        if (SELF_BF16) a[2 + c] = load8bf((const bf16*)self, idx);
        else           a[2 + c] = cvt8((const float*)self + idx);
    }
}

__device__ __forceinline__ short8 load_bfrag(
    const float* __restrict__ Wl, const float* __restrict__ Wr,
    int f, int c, int quad)
{
    if (c < 2) return cvt8(Wl + (long)f * 64 + c * 32 + quad * 8);
    return cvt8(Wr + (long)f * 64 + (c - 2) * 32 + quad * 8);
}

// Layer 1: writes h1 (bf16)
__global__ __launch_bounds__(256) void node_layer1_mfma(
    const float* __restrict__ x, const bf16* __restrict__ mean,
    const float* __restrict__ Wl, const float* __restrict__ bl,
    const float* __restrict__ Wr, bf16* __restrict__ h_out)
{
    int tid = threadIdx.x;
    int wave = tid >> 6, lane = tid & 63;
    int quad = lane >> 4, n16 = lane & 15;
    int nb = (blockIdx.x * 4 + wave) * 16;

    int node_a = nb + n16;
    int na = node_a < N_NODES ? node_a : N_NODES - 1;
    short8 a[4];
    load_afrags<false>(a, mean, x, na, quad);

#pragma unroll
    for (int t = 0; t < 4; t++) {
        int f = 16 * t + n16;
        f32x4 acc = {0.f, 0.f, 0.f, 0.f};
#pragma unroll
        for (int c = 0; c < 4; c++) {
            short8 b = load_bfrag(Wl, Wr, f, c, quad);
            acc = __builtin_amdgcn_mfma_f32_16x16x32_bf16(a[c], b, acc, 0, 0, 0);
        }
        float bias = bl[f];
#pragma unroll
        for (int r = 0; r < 4; r++) {
            int node = nb + quad * 4 + r;
            if (node < N_NODES)
                h_out[(long)node * 64 + f] = __float2bfloat16(fmaxf(acc[r] + bias, 0.0f));
        }
    }
}

// Layer 2 fused with edge-scorer projection; h2 never materialized.
__global__ __launch_bounds__(256) void node_layer2_mfma(
    const bf16* __restrict__ h1, const bf16* __restrict__ mean,
    const float* __restrict__ Wl, const float* __restrict__ bl,
    const float* __restrict__ Wr, const float* __restrict__ Wlin,
    float* __restrict__ s_src, float* __restrict__ s_dst)
{
    int tid = threadIdx.x;
    int wave = tid >> 6, lane = tid & 63;
    int quad = lane >> 4, n16 = lane & 15;
    int nb = (blockIdx.x * 4 + wave) * 16;

    int node_a = nb + n16;
    int na = node_a < N_NODES ? node_a : N_NODES - 1;
    short8 a[4];
    load_afrags<true>(a, mean, h1, na, quad);

    float sa[4] = {0.f, 0.f, 0.f, 0.f};
    float sb[4] = {0.f, 0.f, 0.f, 0.f};
#pragma unroll
    for (int t = 0; t < 4; t++) {
        int f = 16 * t + n16;
        f32x4 acc = {0.f, 0.f, 0.f, 0.f};
#pragma unroll
        for (int c = 0; c < 4; c++) {
            short8 b = load_bfrag(Wl, Wr, f, c, quad);
            acc = __builtin_amdgcn_mfma_f32_16x16x32_bf16(a[c], b, acc, 0, 0, 0);
        }
        float bias = bl[f];
        float wa = Wlin[f];
        float wb = Wlin[64 + f];
#pragma unroll
        for (int r = 0; r < 4; r++) {
            float h = fmaxf(acc[r] + bias, 0.0f);
            sa[r] += h * wa;
            sb[r] += h * wb;
        }
    }
#pragma unroll
    for (int m = 1; m < 16; m <<= 1) {
#pragma unroll
        for (int r = 0; r < 4; r++) {
            sa[r] += __shfl_xor(sa[r], m);
            sb[r] += __shfl_xor(sb[r], m);
        }
    }
    if (n16 == 0) {
#pragma unroll
        for (int r = 0; r < 4; r++) {
            int node = nb + quad * 4 + r;
            if (node < N_NODES) { s_src[node] = sa[r]; s_dst[node] = sb[r]; }
        }
    }
}

__global__ __launch_bounds__(256) void edge_out_kernel(
    const int* __restrict__ src, const int* __restrict__ dst,
    const float* __restrict__ s_src, const float* __restrict__ s_dst,
    const float* __restrict__ blin, float* __restrict__ out)
{
    int e = blockIdx.x * 256 + threadIdx.x;
    if (e >= N_EDGES) return;
    out[e] = s_src[src[e]] + s_dst[dst[e]] + blin[0];
}

extern "C" void kernel_launch(void* const* d_in, const int* in_sizes, int n_in,
                              void* d_out, int out_size, void* d_ws, size_t ws_size,
                              hipStream_t stream) {
    const float* x    = (const float*)d_in[0];
    const int*   ei   = (const int*)d_in[1];
    const float* W1l  = (const float*)d_in[2];
    const float* b1l  = (const float*)d_in[3];
    const float* W1r  = (const float*)d_in[4];
    const float* W2l  = (const float*)d_in[5];
    const float* b2l  = (const float*)d_in[6];
    const float* W2r  = (const float*)d_in[7];
    const float* Wlin = (const float*)d_in[8];
    const float* blin = (const float*)d_in[9];
    float* out = (float*)d_out;

    const int* src = ei;
    const int* dst = ei + N_EDGES;

    // Workspace layout (~34.0 MB total; R2 proved >=39.6 MB is available)
    char* w = (char*)d_ws;
    bf16*  mean = (bf16*)w;  w += (size_t)N_NODES * 64 * 2;   // 12.8 MB (reused by both layers)
    bf16*  h1   = (bf16*)w;  w += (size_t)N_NODES * 64 * 2;   // 12.8 MB
    float* ssrc = (float*)w; w += (size_t)N_NODES * 4;
    float* sdst = (float*)w; w += (size_t)N_NODES * 4;
    int*   deg  = (int*)w;   w += (size_t)N_NODES * 4;
    int*   offs = (int*)w;   w += (size_t)(N_NODES + 4) * 4;  // N+1 used, padded
    int*   woff = (int*)w;   w += (size_t)N_NODES * 4;
    int*   bsum = (int*)w;   w += 4096;                       // SCAN_BLOCKS used
    int*   csr  = (int*)w;   w += (size_t)N_EDGES * 4;        // 6.4 MB

    const int edge_blocks = (N_EDGES + 255) / 256;   // 6250
    const int agg_blocks  = (N_NODES + 3) / 4;       // 25000
    const int node_blocks = (N_NODES + 63) / 64;     // 1563

    // ---- CSR build (once; shared by both layers) ----
    (void)hipMemsetAsync(deg, 0, (size_t)N_NODES * 4, stream);
    hist_kernel<<<edge_blocks, 256, 0, stream>>>(dst, deg);
    scan1_kernel<<<SCAN_BLOCKS, 256, 0, stream>>>(deg, offs, bsum);
    scan2_kernel<<<1, 512, 0, stream>>>(bsum);
    scan3_kernel<<<SCAN_BLOCKS, 256, 0, stream>>>(offs, woff, bsum);
    fill_kernel<<<edge_blocks, 256, 0, stream>>>(src, dst, woff, csr);

    // ---- Layer 1 ----
    aggregate_mean<float><<<agg_blocks, 256, 0, stream>>>(x, offs, csr, mean);
    node_layer1_mfma<<<node_blocks, 256, 0, stream>>>(x, mean, W1l, b1l, W1r, h1);

    // ---- Layer 2 (mean buffer reused) ----
    aggregate_mean<bf16><<<agg_blocks, 256, 0, stream>>>(h1, offs, csr, mean);
    node_layer2_mfma<<<node_blocks, 256, 0, stream>>>(h1, mean, W2l, b2l, W2r, Wlin, ssrc, sdst);

    // ---- Edge scores ----
    edge_out_kernel<<<edge_blocks, 256, 0, stream>>>(src, dst, ssrc, sdst, blin, out);
}

// Round 8
// 398.142 us; speedup vs baseline: 4.0217x; 1.2116x over previous
//
#include <hip/hip_runtime.h>
#include <hip/hip_bf16.h>

#define N_NODES 100000
#define N_EDGES 1600000
#define SCAN_BLOCKS 391          // ceil(100000/256)
#define FILL_RANGES 8            // one node-range per XCD (L2 locality)
#define FILL_CHUNKS 200          // edge chunks per range
#define FILL_CH (N_EDGES / FILL_CHUNKS)   // 8000 edges/chunk
#define RANGE_N (N_NODES / FILL_RANGES)   // 12500 nodes/range

// Float tensors are genuine fp32 (confirmed R3-vs-R5). Internal compute bf16
// via MFMA; output fp32.

typedef __hip_bfloat16 bf16;
typedef short short8 __attribute__((ext_vector_type(8)));
typedef float f32x4 __attribute__((ext_vector_type(4)));
typedef unsigned int uint;

__device__ __forceinline__ short f2bs(float f) {
    bf16 h = __float2bfloat16(f);
    short s; __builtin_memcpy(&s, &h, 2); return s;
}
__device__ __forceinline__ float lo_bf(uint w) {
    uint v = w << 16; float f; __builtin_memcpy(&f, &v, 4); return f;
}
__device__ __forceinline__ float hi_bf(uint w) {
    uint v = w & 0xFFFF0000u; float f; __builtin_memcpy(&f, &v, 4); return f;
}
__device__ __forceinline__ uint pack2(float a, float b) {
    return (uint)(unsigned short)f2bs(a) | ((uint)(unsigned short)f2bs(b) << 16);
}

// 8 consecutive fp32 -> bf16 bits (two float4 loads)
__device__ __forceinline__ short8 cvt8(const float* __restrict__ p) {
    float4 v0 = *(const float4*)p;
    float4 v1 = *(const float4*)(p + 4);
    short8 t;
    t[0] = f2bs(v0.x); t[1] = f2bs(v0.y); t[2] = f2bs(v0.z); t[3] = f2bs(v0.w);
    t[4] = f2bs(v1.x); t[5] = f2bs(v1.y); t[6] = f2bs(v1.z); t[7] = f2bs(v1.w);
    return t;
}
// 8 consecutive bf16 (16B vector load)
__device__ __forceinline__ short8 load8bf(const bf16* __restrict__ p, long idx) {
    return *(const short8*)((const short*)p + idx);
}

// ---- x -> bf16 conversion --------------------------------------------
__global__ __launch_bounds__(256) void convert_kernel(
    const float* __restrict__ in, bf16* __restrict__ out)
{
    int i = blockIdx.x * 256 + threadIdx.x;      // 1.6M threads x 4 elems
    float4 v = ((const float4*)in)[i];
    uint2 o;
    o.x = pack2(v.x, v.y);
    o.y = pack2(v.z, v.w);
    ((uint2*)out)[i] = o;
}

// ---- CSR build --------------------------------------------------------
__global__ __launch_bounds__(256) void hist_kernel(
    const int* __restrict__ dst, int* __restrict__ deg)
{
    int e = blockIdx.x * 256 + threadIdx.x;
    if (e < N_EDGES) atomicAdd(&deg[dst[e]], 1);
}

__global__ __launch_bounds__(256) void scan1_kernel(
    const int* __restrict__ deg, int* __restrict__ offs, int* __restrict__ bsum)
{
    __shared__ int tmp[256];
    int t = threadIdx.x;
    int i = blockIdx.x * 256 + t;
    int v = (i < N_NODES) ? deg[i] : 0;
    tmp[t] = v;
    __syncthreads();
#pragma unroll
    for (int off = 1; off < 256; off <<= 1) {
        int add = (t >= off) ? tmp[t - off] : 0;
        __syncthreads();
        tmp[t] += add;
        __syncthreads();
    }
    if (i < N_NODES) offs[i] = tmp[t] - v;          // exclusive
    if (t == 255) bsum[blockIdx.x] = tmp[255];
}

__global__ __launch_bounds__(512) void scan2_kernel(int* __restrict__ bsum)
{
    __shared__ int tmp[512];
    int t = threadIdx.x;
    int v = (t < SCAN_BLOCKS) ? bsum[t] : 0;
    tmp[t] = v;
    __syncthreads();
#pragma unroll
    for (int off = 1; off < 512; off <<= 1) {
        int add = (t >= off) ? tmp[t - off] : 0;
        __syncthreads();
        tmp[t] += add;
        __syncthreads();
    }
    if (t < SCAN_BLOCKS) bsum[t] = tmp[t] - v;      // exclusive
}

__global__ __launch_bounds__(256) void scan3_kernel(
    int* __restrict__ offs, int* __restrict__ woff, const int* __restrict__ bsum)
{
    int i = blockIdx.x * 256 + threadIdx.x;
    if (i < N_NODES) {
        int v = offs[i] + bsum[blockIdx.x];
        offs[i] = v;
        woff[i] = v;
    }
    if (i == 0) offs[N_NODES] = N_EDGES;
}

// XCD-localized fill: block b -> node range (b&7), edge chunk (b>>3).
// Under round-robin blockIdx->XCD dispatch, each range's csr window (~0.8MB)
// + cursors (~50KB) stay in one XCD's 4MB L2, so scatter lines get fully
// dirtied before eviction (R7: unpartitioned scatter cost 105MB writeback).
// Correctness does not depend on the mapping (device-scope atomics, disjoint
// csr positions).
__global__ __launch_bounds__(256) void fill_kernel(
    const int* __restrict__ src, const int* __restrict__ dst,
    int* __restrict__ woff, int* __restrict__ csr)
{
    int r = blockIdx.x & (FILL_RANGES - 1);
    int c = blockIdx.x >> 3;
    int lo = r * RANGE_N, hi = lo + RANGE_N;
    int e0 = c * FILL_CH;
    for (int e = e0 + threadIdx.x; e < e0 + FILL_CH; e += 256) {
        int d = dst[e];
        if (d >= lo && d < hi) {
            int pos = atomicAdd(&woff[d], 1);
            csr[pos] = src[e];
        }
    }
}

// ---- Mean aggregation (gather, bf16 source) ---------------------------
// Half-wave (32 lanes) per node; lane handles a bf16x2 feature pair.
// Row read = 32 x 4B = 128B coalesced; 2 nodes per wave in flight.
__global__ __launch_bounds__(256) void aggregate_mean(
    const bf16* __restrict__ feat, const int* __restrict__ offs,
    const int* __restrict__ csr, bf16* __restrict__ mean)
{
    int half = threadIdx.x >> 5;
    int l32 = threadIdx.x & 31;
    int n = blockIdx.x * 8 + half;
    if (n >= N_NODES) return;
    int beg = offs[n], end = offs[n + 1];
    const uint* fw = (const uint*)feat;          // row stride 32 words
    float a0 = 0.f, a1 = 0.f;
    int i = beg;
    for (; i + 4 <= end; i += 4) {               // 4 row-gathers in flight
        int s0 = csr[i], s1 = csr[i + 1], s2 = csr[i + 2], s3 = csr[i + 3];
        uint w0 = fw[(long)s0 * 32 + l32];
        uint w1 = fw[(long)s1 * 32 + l32];
        uint w2 = fw[(long)s2 * 32 + l32];
        uint w3 = fw[(long)s3 * 32 + l32];
        a0 += lo_bf(w0) + lo_bf(w1) + lo_bf(w2) + lo_bf(w3);
        a1 += hi_bf(w0) + hi_bf(w1) + hi_bf(w2) + hi_bf(w3);
    }
    for (; i < end; i++) {
        uint w = fw[(long)csr[i] * 32 + l32];
        a0 += lo_bf(w); a1 += hi_bf(w);
    }
    int d = end - beg;
    float inv = d > 0 ? 1.0f / (float)d : 0.0f;
    ((uint*)mean)[(long)n * 32 + l32] = pack2(a0 * inv, a1 * inv);
}

// ---- MFMA node layers -------------------------------------------------
// C[node][f] = relu( mean[node]·Wl[f] + self[node]·Wr[f] + bias[f] )
// K=128 GEMM: A = [mean || self], B = [Wl ; Wr].
// mfma_f32_16x16x32_bf16: A: m=lane&15, k(chunk c) = c*32 + quad*8 + j
// C/D: col=lane&15 (=f), row=quad*4+reg (=node). 16 nodes/wave, 16 MFMA.

__device__ __forceinline__ void load_afrags(
    short8* a, const bf16* __restrict__ mean,
    const bf16* __restrict__ self, int na, int quad)
{
#pragma unroll
    for (int c = 0; c < 2; c++)             // mean part, k = 0..63
        a[c] = load8bf(mean, (long)na * 64 + c * 32 + quad * 8);
#pragma unroll
    for (int c = 0; c < 2; c++)             // self part, k = 64..127
        a[2 + c] = load8bf(self, (long)na * 64 + c * 32 + quad * 8);
}

__device__ __forceinline__ short8 load_bfrag(
    const float* __restrict__ Wl, const float* __restrict__ Wr,
    int f, int c, int quad)
{
    if (c < 2) return cvt8(Wl + (long)f * 64 + c * 32 + quad * 8);
    return cvt8(Wr + (long)f * 64 + (c - 2) * 32 + quad * 8);
}

// Layer 1: writes h1 (bf16). self = xb (pre-converted x).
__global__ __launch_bounds__(256) void node_layer1_mfma(
    const bf16* __restrict__ xb, const bf16* __restrict__ mean,
    const float* __restrict__ Wl, const float* __restrict__ bl,
    const float* __restrict__ Wr, bf16* __restrict__ h_out)
{
    int tid = threadIdx.x;
    int wave = tid >> 6, lane = tid & 63;
    int quad = lane >> 4, n16 = lane & 15;
    int nb = (blockIdx.x * 4 + wave) * 16;

    int node_a = nb + n16;
    int na = node_a < N_NODES ? node_a : N_NODES - 1;
    short8 a[4];
    load_afrags(a, mean, xb, na, quad);

#pragma unroll
    for (int t = 0; t < 4; t++) {
        int f = 16 * t + n16;
        f32x4 acc = {0.f, 0.f, 0.f, 0.f};
#pragma unroll
        for (int c = 0; c < 4; c++) {
            short8 b = load_bfrag(Wl, Wr, f, c, quad);
            acc = __builtin_amdgcn_mfma_f32_16x16x32_bf16(a[c], b, acc, 0, 0, 0);
        }
        float bias = bl[f];
#pragma unroll
        for (int r = 0; r < 4; r++) {
            int node = nb + quad * 4 + r;
            if (node < N_NODES)
                h_out[(long)node * 64 + f] = __float2bfloat16(fmaxf(acc[r] + bias, 0.0f));
        }
    }
}

// Layer 2 fused with edge-scorer projection; h2 never materialized.
__global__ __launch_bounds__(256) void node_layer2_mfma(
    const bf16* __restrict__ h1, const bf16* __restrict__ mean,
    const float* __restrict__ Wl, const float* __restrict__ bl,
    const float* __restrict__ Wr, const float* __restrict__ Wlin,
    float* __restrict__ s_src, float* __restrict__ s_dst)
{
    int tid = threadIdx.x;
    int wave = tid >> 6, lane = tid & 63;
    int quad = lane >> 4, n16 = lane & 15;
    int nb = (blockIdx.x * 4 + wave) * 16;

    int node_a = nb + n16;
    int na = node_a < N_NODES ? node_a : N_NODES - 1;
    short8 a[4];
    load_afrags(a, mean, h1, na, quad);

    float sa[4] = {0.f, 0.f, 0.f, 0.f};
    float sb[4] = {0.f, 0.f, 0.f, 0.f};
#pragma unroll
    for (int t = 0; t < 4; t++) {
        int f = 16 * t + n16;
        f32x4 acc = {0.f, 0.f, 0.f, 0.f};
#pragma unroll
        for (int c = 0; c < 4; c++) {
            short8 b = load_bfrag(Wl, Wr, f, c, quad);
            acc = __builtin_amdgcn_mfma_f32_16x16x32_bf16(a[c], b, acc, 0, 0, 0);
        }
        float bias = bl[f];
        float wa = Wlin[f];
        float wb = Wlin[64 + f];
#pragma unroll
        for (int r = 0; r < 4; r++) {
            float h = fmaxf(acc[r] + bias, 0.0f);
            sa[r] += h * wa;
            sb[r] += h * wb;
        }
    }
#pragma unroll
    for (int m = 1; m < 16; m <<= 1) {
#pragma unroll
        for (int r = 0; r < 4; r++) {
            sa[r] += __shfl_xor(sa[r], m);
            sb[r] += __shfl_xor(sb[r], m);
        }
    }
    if (n16 == 0) {
#pragma unroll
        for (int r = 0; r < 4; r++) {
            int node = nb + quad * 4 + r;
            if (node < N_NODES) { s_src[node] = sa[r]; s_dst[node] = sb[r]; }
        }
    }
}

__global__ __launch_bounds__(256) void edge_out_kernel(
    const int* __restrict__ src, const int* __restrict__ dst,
    const float* __restrict__ s_src, const float* __restrict__ s_dst,
    const float* __restrict__ blin, float* __restrict__ out)
{
    int e = blockIdx.x * 256 + threadIdx.x;
    if (e >= N_EDGES) return;
    out[e] = s_src[src[e]] + s_dst[dst[e]] + blin[0];
}

extern "C" void kernel_launch(void* const* d_in, const int* in_sizes, int n_in,
                              void* d_out, int out_size, void* d_ws, size_t ws_size,
                              hipStream_t stream) {
    const float* x    = (const float*)d_in[0];
    const int*   ei   = (const int*)d_in[1];
    const float* W1l  = (const float*)d_in[2];
    const float* b1l  = (const float*)d_in[3];
    const float* W1r  = (const float*)d_in[4];
    const float* W2l  = (const float*)d_in[5];
    const float* b2l  = (const float*)d_in[6];
    const float* W2r  = (const float*)d_in[7];
    const float* Wlin = (const float*)d_in[8];
    const float* blin = (const float*)d_in[9];
    float* out = (float*)d_out;

    const int* src = ei;
    const int* dst = ei + N_EDGES;

    // Workspace (~46.8 MB)
    char* w = (char*)d_ws;
    bf16*  xb   = (bf16*)w;  w += (size_t)N_NODES * 64 * 2;   // 12.8 MB
    bf16*  mean = (bf16*)w;  w += (size_t)N_NODES * 64 * 2;   // 12.8 MB (reused)
    bf16*  h1   = (bf16*)w;  w += (size_t)N_NODES * 64 * 2;   // 12.8 MB
    float* ssrc = (float*)w; w += (size_t)N_NODES * 4;
    float* sdst = (float*)w; w += (size_t)N_NODES * 4;
    int*   deg  = (int*)w;   w += (size_t)N_NODES * 4;
    int*   offs = (int*)w;   w += (size_t)(N_NODES + 4) * 4;
    int*   woff = (int*)w;   w += (size_t)N_NODES * 4;
    int*   bsum = (int*)w;   w += 4096;
    int*   csr  = (int*)w;   w += (size_t)N_EDGES * 4;        // 6.4 MB

    const int edge_blocks = (N_EDGES + 255) / 256;   // 6250
    const int conv_blocks = (N_NODES * 64 / 4) / 256;// 6250
    const int agg_blocks  = (N_NODES + 7) / 8;       // 12500
    const int node_blocks = (N_NODES + 63) / 64;     // 1563

    // ---- x -> bf16 + CSR build ----
    convert_kernel<<<conv_blocks, 256, 0, stream>>>(x, xb);
    (void)hipMemsetAsync(deg, 0, (size_t)N_NODES * 4, stream);
    hist_kernel<<<edge_blocks, 256, 0, stream>>>(dst, deg);
    scan1_kernel<<<SCAN_BLOCKS, 256, 0, stream>>>(deg, offs, bsum);
    scan2_kernel<<<1, 512, 0, stream>>>(bsum);
    scan3_kernel<<<SCAN_BLOCKS, 256, 0, stream>>>(offs, woff, bsum);
    fill_kernel<<<FILL_RANGES * FILL_CHUNKS, 256, 0, stream>>>(src, dst, woff, csr);

    // ---- Layer 1 ----
    aggregate_mean<<<agg_blocks, 256, 0, stream>>>(xb, offs, csr, mean);
    node_layer1_mfma<<<node_blocks, 256, 0, stream>>>(xb, mean, W1l, b1l, W1r, h1);

    // ---- Layer 2 (mean buffer reused) ----
    aggregate_mean<<<agg_blocks, 256, 0, stream>>>(h1, offs, csr, mean);
    node_layer2_mfma<<<node_blocks, 256, 0, stream>>>(h1, mean, W2l, b2l, W2r, Wlin, ssrc, sdst);

    // ---- Edge scores ----
    edge_out_kernel<<<edge_blocks, 256, 0, stream>>>(src, dst, ssrc, sdst, blin, out);
}